// Round 5
// baseline (1196.639 us; speedup 1.0000x reference)
//
#include <hip/hip_runtime.h>
#include <hip/hip_fp16.h>

#define VOCAB 128
#define TMAX 16

typedef _Float16 f16;
typedef _Float16 f16x4 __attribute__((ext_vector_type(4)));
typedef _Float16 f16x8 __attribute__((ext_vector_type(8)));
typedef float f32x4 __attribute__((ext_vector_type(4)));

// ---- kernel 1: gih[dir][v][col(256)][gate(4)] = emb[v].Wih[gate*256+col] + b
__global__ void gih_kernel(const float* __restrict__ emb,
                           const float* __restrict__ WihF, const float* __restrict__ bF,
                           const float* __restrict__ WihB, const float* __restrict__ bB,
                           f16* __restrict__ gih) {
    int dir = blockIdx.x >> 7;      // 256 blocks: 2 dirs x 128 vocab
    int v   = blockIdx.x & 127;
    const float* Wih = dir ? WihB : WihF;
    const float* bb  = dir ? bB : bF;
    __shared__ float ev[128];
    int t = threadIdx.x;            // 256 threads
    if (t < 128) ev[t] = emb[v*128 + t];
    __syncthreads();
#pragma unroll
    for (int qq = 0; qq < 4; ++qq) {
        int g = qq*256 + t;         // gate=qq, col=t
        const float4* w4 = (const float4*)(Wih + (size_t)g * 128);
        float s = bb[g];
#pragma unroll
        for (int e = 0; e < 32; ++e) {
            float4 wv = w4[e];
            s += wv.x*ev[e*4] + wv.y*ev[e*4+1] + wv.z*ev[e*4+2] + wv.w*ev[e*4+3];
        }
        gih[((size_t)(dir*VOCAB + v)*256 + t)*4 + qq] = (f16)s;
    }
}

// ---- kernel 2: pack Whh f32[1024][256] -> f16 bp[dir][jj(16)][gate(4)][kt(8)][lane(64)][e(8)]
// B-fragment (16x16x32): col = lane&15, k = kt*32 + (lane>>4)*8 + e
__global__ void whh_pack_kernel(const float* __restrict__ WhhF,
                                const float* __restrict__ WhhB,
                                f16* __restrict__ bp) {
    int idx = blockIdx.x * 256 + threadIdx.x;   // grid 2048 -> 524288 = 2*1024*256
    int dir = idx >> 18;
    int rem = idx & 262143;
    int g = rem >> 8;       // 0..1023
    int k = rem & 255;
    const float* W = dir ? WhhB : WhhF;
    float val = W[(size_t)g * 256 + k];
    int gate = g >> 8;
    int jj   = (g >> 4) & 15;
    int c15  = g & 15;
    int kt = k >> 5, kr = (k >> 3) & 3, e = k & 7;
    int lane = kr*16 + c15;
    size_t off = ((((size_t)(dir*16 + jj)*4 + gate)*8 + kt)*64 + lane)*8 + e;
    bp[off] = (f16)val;
}

// ---- kernel 3: LSTM, column-ownership.
// 512 blocks (dir = b&1, 64 seqs each) x 512 threads (8 waves).
// Wave w owns output col-tiles jj = w and w+8 (16 cols x 4 gates each);
// B fragments live in 128 VGPRs, streamed from L2 once per phase.
// h: double-buffered XOR-swizzled LDS; c: bank-swizzled LDS; 1 barrier/step.
__global__ __launch_bounds__(512, 2)
void lstm_kernel(const int* __restrict__ char_ids, const int* __restrict__ lengths,
                 const f16* __restrict__ gih, const f16* __restrict__ bp2,
                 float* __restrict__ out) {
    const int dir  = blockIdx.x & 1;
    const int grp  = blockIdx.x >> 1;
    const int seq0 = grp * 64;

    __shared__ __align__(16) unsigned char h2[2][32768];   // 2 x [64][256] f16, swizzled
    __shared__ __align__(16) float c_lds[16384];           // [64][256] f32, bank-hashed
    __shared__ int cid_s[1024];                            // [64][16]
    __shared__ int len_s[64];

    const int tid  = threadIdx.x;
    const int lane = tid & 63;
    const int w    = tid >> 6;
    const int l15  = lane & 15;
    const int q    = lane >> 4;

    // prologue
#pragma unroll
    for (int i = 0; i < 2; ++i)
        cid_s[i*512 + tid] = char_ids[(size_t)seq0*16 + i*512 + tid];
    if (tid < 64) len_s[tid] = lengths[seq0 + tid];
    {
        float4 z = {0.f, 0.f, 0.f, 0.f};
#pragma unroll
        for (int i = 0; i < 4; ++i) *(float4*)(h2[0] + (i*512 + tid)*16) = z;
#pragma unroll
        for (int i = 0; i < 8; ++i) *(float4*)(c_lds + (i*512 + tid)*4) = z;
    }
    __syncthreads();

    const f16* bp_d  = bp2 + (size_t)dir * 262144;
    const f16* gih_d = gih + (size_t)dir * 131072;

    unsigned char* hc = h2[0];
    unsigned char* hb = h2[1];

    // lane-local h carry (rows m*16+q*4+r, col jj*16+l15), per phase
    f16 hA[4][4], hB[4][4];
#pragma unroll
    for (int m_ = 0; m_ < 4; ++m_)
#pragma unroll
        for (int r = 0; r < 4; ++r) { hA[m_][r] = (f16)0.f; hB[m_][r] = (f16)0.f; }

    int tt = dir ? 15 : 0;
    const int dtt = dir ? -1 : 1;

#pragma unroll 1
    for (int s = 0; s < TMAX; ++s) {
#pragma unroll 1
        for (int ph = 0; ph < 2; ++ph) {          // unroll 1: only ONE B set live
            const int jj = w + ph*8;
            const f16* bpj = bp_d + (size_t)jj * 16384;
            f16x8 B[4][8];                         // 128 VGPR, from L2
#pragma unroll
            for (int g = 0; g < 4; ++g)
#pragma unroll
                for (int kt = 0; kt < 8; ++kt)
                    B[g][kt] = *(const f16x8*)(bpj + ((g*8 + kt)*64 + lane)*8);

#pragma unroll
            for (int m = 0; m < 4; ++m) {
                const int row0 = m*16 + q*4;
                f16x4 grow[4];
                int lenr[4];
#pragma unroll
                for (int r = 0; r < 4; ++r) {
                    int row = row0 + r;
                    int cid = cid_s[row*16 + tt];              // LDS broadcast
                    grow[r] = *(const f16x4*)(gih_d + ((size_t)cid*256 + jj*16 + l15)*4);
                    lenr[r] = len_s[row];
                }
                f32x4 acc[4];
#pragma unroll
                for (int g = 0; g < 4; ++g) acc[g] = (f32x4){0.f,0.f,0.f,0.f};
                const int arow = m*16 + l15;
                const int aswz = (arow & 7) << 4;
#pragma unroll
                for (int half = 0; half < 2; ++half) {
                    f16x8 a[4];
#pragma unroll
                    for (int k = 0; k < 4; ++k) {
                        int off = (arow*512 + ((half*4 + k)*32 + q*8)*2) ^ aswz;
                        a[k] = *(const f16x8*)(hc + off);
                    }
#pragma unroll
                    for (int g = 0; g < 4; ++g)
#pragma unroll
                        for (int k = 0; k < 4; ++k)
                            acc[g] = __builtin_amdgcn_mfma_f32_16x16x32_f16(
                                a[k], B[g][half*4 + k], acc[g], 0, 0, 0);
                }
                // epilogue: lane owns (row0+r, col jj*16+l15)
#pragma unroll
                for (int r = 0; r < 4; ++r) {
                    const int row = row0 + r;
                    float gi = acc[0][r] + (float)grow[r][0];
                    float gf = acc[1][r] + (float)grow[r][1];
                    float gg = acc[2][r] + (float)grow[r][2];
                    float go = acc[3][r] + (float)grow[r][3];
                    float i_ = 1.f/(1.f + __expf(-gi));
                    float f_ = 1.f/(1.f + __expf(-gf));
                    float zg = __expf(2.f*gg);
                    float g_ = 1.f - 2.f/(zg + 1.f);
                    float o_ = 1.f/(1.f + __expf(-go));
                    const int col  = jj*16 + l15;
                    const int cidx = row*256 + (col ^ ((row & 4) << 2));  // bank hash
                    float cold = c_lds[cidx];
                    float cn = f_*cold + i_*g_;
                    bool upd = tt < lenr[r];
                    float cw = upd ? cn : cold;
                    c_lds[cidx] = cw;
                    float zt = __expf(2.f*cn);
                    float th = 1.f - 2.f/(zt + 1.f);
                    float hnv = o_*th;
                    f16 hold = (ph == 0) ? hA[m][r] : hB[m][r];
                    f16 hw = upd ? (f16)hnv : hold;
                    if (ph == 0) hA[m][r] = hw; else hB[m][r] = hw;
                    int hoff = (row*512 + col*2) ^ ((row & 7) << 4);
                    *(f16*)(hb + hoff) = hw;
                }
            }
        }
        __syncthreads();   // all h-writes visible; all reads of hc done
        unsigned char* tmp = hc; hc = hb; hb = tmp;
        tt += dtt;
    }

    // out: f32 [16384][512]; block writes 64 seqs x its dir's 256 cols
#pragma unroll
    for (int i = 0; i < 32; ++i) {
        int idx  = i*512 + tid;
        int srow = idx >> 8, col = idx & 255;
        int off  = (srow*512 + col*2) ^ ((srow & 7) << 4);
        f16 hv   = *(const f16*)(hc + off);
        out[(size_t)(seq0 + srow)*512 + dir*256 + col] = (float)hv;
    }
}

// ---------------------------------------------------------------------------
extern "C" void kernel_launch(void* const* d_in, const int* in_sizes, int n_in,
                              void* d_out, int out_size, void* d_ws, size_t ws_size,
                              hipStream_t stream) {
    (void)in_sizes; (void)n_in; (void)out_size; (void)ws_size;
    const int*   char_ids = (const int*)d_in[0];
    const int*   lengths  = (const int*)d_in[1];
    const float* emb      = (const float*)d_in[2];
    const float* Wih_f    = (const float*)d_in[3];
    const float* Whh_f    = (const float*)d_in[4];
    const float* b_f      = (const float*)d_in[5];
    const float* Wih_b    = (const float*)d_in[6];
    const float* Whh_b    = (const float*)d_in[7];
    const float* b_b      = (const float*)d_in[8];
    float* out = (float*)d_out;

    f16* gih = (f16*)d_ws;                    // 2*128*256*4 f16 = 512 KB
    f16* bp  = gih + 2 * VOCAB * 1024;        // 2*16*4*8*64*8 f16 = 1 MB

    gih_kernel<<<256, 256, 0, stream>>>(emb, Wih_f, b_f, Wih_b, b_b, gih);
    whh_pack_kernel<<<2048, 256, 0, stream>>>(Whh_f, Whh_b, bp);
    lstm_kernel<<<512, 512, 0, stream>>>(char_ids, lengths, gih, bp, out);
}

// Round 6
// 1194.755 us; speedup vs baseline: 1.0016x; 1.0016x over previous
//
#include <hip/hip_runtime.h>
#include <hip/hip_fp16.h>

#define VOCAB 128
#define TMAX 16

typedef _Float16 f16;
typedef _Float16 f16x4 __attribute__((ext_vector_type(4)));
typedef _Float16 f16x8 __attribute__((ext_vector_type(8)));
typedef float f32x4 __attribute__((ext_vector_type(4)));

// ---- kernel 1: gih[dir][v][col(256)][gate(4)] = emb[v].Wih[gate*256+col] + b
__global__ void gih_kernel(const float* __restrict__ emb,
                           const float* __restrict__ WihF, const float* __restrict__ bF,
                           const float* __restrict__ WihB, const float* __restrict__ bB,
                           f16* __restrict__ gih) {
    int dir = blockIdx.x >> 7;      // 256 blocks: 2 dirs x 128 vocab
    int v   = blockIdx.x & 127;
    const float* Wih = dir ? WihB : WihF;
    const float* bb  = dir ? bB : bF;
    __shared__ float ev[128];
    int t = threadIdx.x;            // 256 threads
    if (t < 128) ev[t] = emb[v*128 + t];
    __syncthreads();
#pragma unroll
    for (int qq = 0; qq < 4; ++qq) {
        int g = qq*256 + t;         // gate=qq, col=t
        const float4* w4 = (const float4*)(Wih + (size_t)g * 128);
        float s = bb[g];
#pragma unroll
        for (int e = 0; e < 32; ++e) {
            float4 wv = w4[e];
            s += wv.x*ev[e*4] + wv.y*ev[e*4+1] + wv.z*ev[e*4+2] + wv.w*ev[e*4+3];
        }
        gih[((size_t)(dir*VOCAB + v)*256 + t)*4 + qq] = (f16)s;
    }
}

// ---- kernel 2: pack Whh f32[1024][256] -> f16 bp[dir][jj(16)][gate(4)][kt(8)][lane(64)][e(8)]
// B-fragment (16x16x32): col = lane&15, k = kt*32 + (lane>>4)*8 + e
__global__ void whh_pack_kernel(const float* __restrict__ WhhF,
                                const float* __restrict__ WhhB,
                                f16* __restrict__ bp) {
    int idx = blockIdx.x * 256 + threadIdx.x;   // grid 2048 -> 524288 = 2*1024*256
    int dir = idx >> 18;
    int rem = idx & 262143;
    int g = rem >> 8;       // 0..1023
    int k = rem & 255;
    const float* W = dir ? WhhB : WhhF;
    float val = W[(size_t)g * 256 + k];
    int gate = g >> 8;
    int jj   = (g >> 4) & 15;
    int c15  = g & 15;
    int kt = k >> 5, kr = (k >> 3) & 3, e = k & 7;
    int lane = kr*16 + c15;
    size_t off = ((((size_t)(dir*16 + jj)*4 + gate)*8 + kt)*64 + lane)*8 + e;
    bp[off] = (f16)val;
}

// ---- kernel 3: LSTM, column-ownership.
// 512 blocks (dir = b&1, 64 seqs each) x 512 threads (8 waves).
// Wave w owns output col-tiles jj = w and w+8 (16 cols x 4 gates each);
// B fragments live in 128 VGPRs, streamed from L2 once per phase.
// h: double-buffered XOR-swizzled LDS; c: bank-swizzled LDS; 1 barrier/step.
// launch_bounds(512, 1): arg2 behaves as MIN BLOCKS/CU (measured: (512,2)->128
// VGPR cap, (256,1)->256). 1 block/CU => 2 waves/SIMD => 256-VGPR cap, no spill.
__global__ __launch_bounds__(512, 1)
void lstm_kernel(const int* __restrict__ char_ids, const int* __restrict__ lengths,
                 const f16* __restrict__ gih, const f16* __restrict__ bp2,
                 float* __restrict__ out) {
    const int dir  = blockIdx.x & 1;
    const int grp  = blockIdx.x >> 1;
    const int seq0 = grp * 64;

    __shared__ __align__(16) unsigned char h2[2][32768];   // 2 x [64][256] f16, swizzled
    __shared__ __align__(16) float c_lds[16384];           // [64][256] f32, bank-hashed
    __shared__ int cid_s[1024];                            // [64][16]
    __shared__ int len_s[64];

    const int tid  = threadIdx.x;
    const int lane = tid & 63;
    const int w    = tid >> 6;
    const int l15  = lane & 15;
    const int q    = lane >> 4;

    // prologue
#pragma unroll
    for (int i = 0; i < 2; ++i)
        cid_s[i*512 + tid] = char_ids[(size_t)seq0*16 + i*512 + tid];
    if (tid < 64) len_s[tid] = lengths[seq0 + tid];
    {
        float4 z = {0.f, 0.f, 0.f, 0.f};
#pragma unroll
        for (int i = 0; i < 4; ++i) *(float4*)(h2[0] + (i*512 + tid)*16) = z;
#pragma unroll
        for (int i = 0; i < 8; ++i) *(float4*)(c_lds + (i*512 + tid)*4) = z;
    }
    __syncthreads();

    const f16* bp_d  = bp2 + (size_t)dir * 262144;
    const f16* gih_d = gih + (size_t)dir * 131072;

    unsigned char* hc = h2[0];
    unsigned char* hb = h2[1];

    // lane-local h carry (rows m*16+q*4+r, col jj*16+l15), per phase
    f16 hA[4][4], hB[4][4];
#pragma unroll
    for (int m_ = 0; m_ < 4; ++m_)
#pragma unroll
        for (int r = 0; r < 4; ++r) { hA[m_][r] = (f16)0.f; hB[m_][r] = (f16)0.f; }

    int tt = dir ? 15 : 0;
    const int dtt = dir ? -1 : 1;

#pragma unroll 1
    for (int s = 0; s < TMAX; ++s) {
#pragma unroll 1
        for (int ph = 0; ph < 2; ++ph) {          // unroll 1: only ONE B set live
            const int jj = w + ph*8;
            const f16* bpj = bp_d + (size_t)jj * 16384;
            f16x8 B[4][8];                         // 128 VGPR, from L2
#pragma unroll
            for (int g = 0; g < 4; ++g)
#pragma unroll
                for (int kt = 0; kt < 8; ++kt)
                    B[g][kt] = *(const f16x8*)(bpj + ((g*8 + kt)*64 + lane)*8);

#pragma unroll
            for (int m = 0; m < 4; ++m) {
                const int row0 = m*16 + q*4;
                f16x4 grow[4];
                int lenr[4];
#pragma unroll
                for (int r = 0; r < 4; ++r) {
                    int row = row0 + r;
                    int cid = cid_s[row*16 + tt];              // LDS broadcast
                    grow[r] = *(const f16x4*)(gih_d + ((size_t)cid*256 + jj*16 + l15)*4);
                    lenr[r] = len_s[row];
                }
                f32x4 acc[4];
#pragma unroll
                for (int g = 0; g < 4; ++g) acc[g] = (f32x4){0.f,0.f,0.f,0.f};
                const int arow = m*16 + l15;
                const int aswz = (arow & 7) << 4;
#pragma unroll
                for (int half = 0; half < 2; ++half) {
                    f16x8 a[4];
#pragma unroll
                    for (int k = 0; k < 4; ++k) {
                        int off = (arow*512 + ((half*4 + k)*32 + q*8)*2) ^ aswz;
                        a[k] = *(const f16x8*)(hc + off);
                    }
#pragma unroll
                    for (int g = 0; g < 4; ++g)
#pragma unroll
                        for (int k = 0; k < 4; ++k)
                            acc[g] = __builtin_amdgcn_mfma_f32_16x16x32_f16(
                                a[k], B[g][half*4 + k], acc[g], 0, 0, 0);
                }
                // epilogue: lane owns (row0+r, col jj*16+l15)
#pragma unroll
                for (int r = 0; r < 4; ++r) {
                    const int row = row0 + r;
                    float gi = acc[0][r] + (float)grow[r][0];
                    float gf = acc[1][r] + (float)grow[r][1];
                    float gg = acc[2][r] + (float)grow[r][2];
                    float go = acc[3][r] + (float)grow[r][3];
                    float i_ = 1.f/(1.f + __expf(-gi));
                    float f_ = 1.f/(1.f + __expf(-gf));
                    float zg = __expf(2.f*gg);
                    float g_ = 1.f - 2.f/(zg + 1.f);
                    float o_ = 1.f/(1.f + __expf(-go));
                    const int col  = jj*16 + l15;
                    const int cidx = row*256 + (col ^ ((row & 4) << 2));  // bank hash
                    float cold = c_lds[cidx];
                    float cn = f_*cold + i_*g_;
                    bool upd = tt < lenr[r];
                    float cw = upd ? cn : cold;
                    c_lds[cidx] = cw;
                    float zt = __expf(2.f*cn);
                    float th = 1.f - 2.f/(zt + 1.f);
                    float hnv = o_*th;
                    f16 hold = (ph == 0) ? hA[m][r] : hB[m][r];
                    f16 hw = upd ? (f16)hnv : hold;
                    if (ph == 0) hA[m][r] = hw; else hB[m][r] = hw;
                    int hoff = (row*512 + col*2) ^ ((row & 7) << 4);
                    *(f16*)(hb + hoff) = hw;
                }
            }
        }
        __syncthreads();   // all h-writes visible; all reads of hc done
        unsigned char* tmp = hc; hc = hb; hb = tmp;
        tt += dtt;
    }

    // out: f32 [16384][512]; block writes 64 seqs x its dir's 256 cols
#pragma unroll
    for (int i = 0; i < 32; ++i) {
        int idx  = i*512 + tid;
        int srow = idx >> 8, col = idx & 255;
        int off  = (srow*512 + col*2) ^ ((srow & 7) << 4);
        f16 hv   = *(const f16*)(hc + off);
        out[(size_t)(seq0 + srow)*512 + dir*256 + col] = (float)hv;
    }
}

// ---------------------------------------------------------------------------
extern "C" void kernel_launch(void* const* d_in, const int* in_sizes, int n_in,
                              void* d_out, int out_size, void* d_ws, size_t ws_size,
                              hipStream_t stream) {
    (void)in_sizes; (void)n_in; (void)out_size; (void)ws_size;
    const int*   char_ids = (const int*)d_in[0];
    const int*   lengths  = (const int*)d_in[1];
    const float* emb      = (const float*)d_in[2];
    const float* Wih_f    = (const float*)d_in[3];
    const float* Whh_f    = (const float*)d_in[4];
    const float* b_f      = (const float*)d_in[5];
    const float* Wih_b    = (const float*)d_in[6];
    const float* Whh_b    = (const float*)d_in[7];
    const float* b_b      = (const float*)d_in[8];
    float* out = (float*)d_out;

    f16* gih = (f16*)d_ws;                    // 2*128*256*4 f16 = 512 KB
    f16* bp  = gih + 2 * VOCAB * 1024;        // 2*16*4*8*64*8 f16 = 1 MB

    gih_kernel<<<256, 256, 0, stream>>>(emb, Wih_f, b_f, Wih_b, b_b, gih);
    whh_pack_kernel<<<2048, 256, 0, stream>>>(Whh_f, Whh_b, bp);
    lstm_kernel<<<512, 512, 0, stream>>>(char_ids, lengths, gih, bp, out);
}

// Round 8
// 784.255 us; speedup vs baseline: 1.5258x; 1.5234x over previous
//
#include <hip/hip_runtime.h>
#include <hip/hip_fp16.h>

#define VOCAB 128
#define TMAX 16

typedef _Float16 f16;
typedef _Float16 f16x4 __attribute__((ext_vector_type(4)));
typedef _Float16 f16x8 __attribute__((ext_vector_type(8)));
typedef float f32x4 __attribute__((ext_vector_type(4)));

// ---- kernel 1: gih[dir][v][col(256)][gate(4)] = emb[v].Wih[gate*256+col] + b
__global__ void gih_kernel(const float* __restrict__ emb,
                           const float* __restrict__ WihF, const float* __restrict__ bF,
                           const float* __restrict__ WihB, const float* __restrict__ bB,
                           f16* __restrict__ gih) {
    int dir = blockIdx.x >> 7;      // 256 blocks: 2 dirs x 128 vocab
    int v   = blockIdx.x & 127;
    const float* Wih = dir ? WihB : WihF;
    const float* bb  = dir ? bB : bF;
    __shared__ float ev[128];
    int t = threadIdx.x;            // 256 threads
    if (t < 128) ev[t] = emb[v*128 + t];
    __syncthreads();
#pragma unroll
    for (int qq = 0; qq < 4; ++qq) {
        int g = qq*256 + t;         // gate=qq, col=t
        const float4* w4 = (const float4*)(Wih + (size_t)g * 128);
        float s = bb[g];
#pragma unroll
        for (int e = 0; e < 32; ++e) {
            float4 wv = w4[e];
            s += wv.x*ev[e*4] + wv.y*ev[e*4+1] + wv.z*ev[e*4+2] + wv.w*ev[e*4+3];
        }
        gih[((size_t)(dir*VOCAB + v)*256 + t)*4 + qq] = (f16)s;
    }
}

// ---- kernel 2: pack Whh f32[1024][256] -> f16 bp[dir][jj(16)][gate(4)][kt(8)][lane(64)][e(8)]
// B-fragment (16x16x32): col = lane&15, k = kt*32 + (lane>>4)*8 + e
__global__ void whh_pack_kernel(const float* __restrict__ WhhF,
                                const float* __restrict__ WhhB,
                                f16* __restrict__ bp) {
    int idx = blockIdx.x * 256 + threadIdx.x;   // grid 2048 -> 524288 = 2*1024*256
    int dir = idx >> 18;
    int rem = idx & 262143;
    int g = rem >> 8;       // 0..1023
    int k = rem & 255;
    const float* W = dir ? WhhB : WhhF;
    float val = W[(size_t)g * 256 + k];
    int gate = g >> 8;
    int jj   = (g >> 4) & 15;
    int c15  = g & 15;
    int kt = k >> 5, kr = (k >> 3) & 3, e = k & 7;
    int lane = kr*16 + c15;
    size_t off = ((((size_t)(dir*16 + jj)*4 + gate)*8 + kt)*64 + lane)*8 + e;
    bp[off] = (f16)val;
}

// ---- kernel 3: LSTM, column-ownership, 256-thread blocks.
// 1024 blocks (dir = b&1, 32 seqs each) x 256 threads (4 waves).
// Wave w owns col-tiles jj = w*4+p, p=0..3 (4 phases/step, one B set live).
// Measured VGPR budget ~= 65536/block_threads: 256 thr -> 256 regs (r2),
// 512 thr -> 128 regs (r5/r6, spilled). 256-thr blocks + demand ~200 => no spill.
// h: double-buffered XOR-swizzled LDS; "old h" re-read from hc (no reg carry,
// avoids dynamic-index scratch); c: bank-hashed LDS; 1 barrier/step.
__global__ __launch_bounds__(256, 1)
void lstm_kernel(const int* __restrict__ char_ids, const int* __restrict__ lengths,
                 const f16* __restrict__ gih, const f16* __restrict__ bp2,
                 float* __restrict__ out) {
    const int dir  = blockIdx.x & 1;
    const int grp  = blockIdx.x >> 1;
    const int seq0 = grp * 32;

    __shared__ __align__(16) unsigned char h2[2][16384];   // 2 x [32][256] f16, swizzled
    __shared__ __align__(16) float c_lds[8192];            // [32][256] f32, bank-hashed
    __shared__ int cid_s[512];                             // [32][16]
    __shared__ int len_s[32];

    const int tid  = threadIdx.x;
    const int lane = tid & 63;
    const int w    = tid >> 6;      // 0..3
    const int l15  = lane & 15;
    const int q    = lane >> 4;

    // prologue
#pragma unroll
    for (int i = 0; i < 2; ++i)
        cid_s[i*256 + tid] = char_ids[(size_t)seq0*16 + i*256 + tid];
    if (tid < 32) len_s[tid] = lengths[seq0 + tid];
    {
        float4 z = {0.f, 0.f, 0.f, 0.f};
#pragma unroll
        for (int i = 0; i < 4; ++i) *(float4*)(h2[0] + (i*256 + tid)*16) = z;
#pragma unroll
        for (int i = 0; i < 8; ++i) *(float4*)(c_lds + (i*256 + tid)*4) = z;
    }
    __syncthreads();

    const f16* bp_d  = bp2 + (size_t)dir * 262144;
    const f16* gih_d = gih + (size_t)dir * 131072;

    unsigned char* hc = h2[0];
    unsigned char* hb = h2[1];

    int tt = dir ? 15 : 0;
    const int dtt = dir ? -1 : 1;

#pragma unroll 1
    for (int s = 0; s < TMAX; ++s) {
#pragma unroll 1
        for (int p = 0; p < 4; ++p) {             // unroll 1: only ONE B set live
            const int jj = w*4 + p;
            const f16* bpj = bp_d + (size_t)jj * 16384;
            f16x8 B[4][8];                         // 128 VGPR, from L2
#pragma unroll
            for (int g = 0; g < 4; ++g)
#pragma unroll
                for (int kt = 0; kt < 8; ++kt)
                    B[g][kt] = *(const f16x8*)(bpj + ((g*8 + kt)*64 + lane)*8);

#pragma unroll
            for (int m = 0; m < 2; ++m) {
                const int row0 = m*16 + q*4;
                f16x4 grow[4];
                int lenr[4];
#pragma unroll
                for (int r = 0; r < 4; ++r) {
                    int row = row0 + r;
                    int cid = cid_s[row*16 + tt];              // LDS broadcast
                    grow[r] = *(const f16x4*)(gih_d + ((size_t)cid*256 + jj*16 + l15)*4);
                    lenr[r] = len_s[row];
                }
                f32x4 acc[4];
#pragma unroll
                for (int g = 0; g < 4; ++g) acc[g] = (f32x4){0.f,0.f,0.f,0.f};
                const int arow = m*16 + l15;
                const int aswz = (arow & 7) << 4;
#pragma unroll
                for (int half = 0; half < 2; ++half) {
                    f16x8 a[4];
#pragma unroll
                    for (int k = 0; k < 4; ++k) {
                        int off = (arow*512 + ((half*4 + k)*32 + q*8)*2) ^ aswz;
                        a[k] = *(const f16x8*)(hc + off);
                    }
#pragma unroll
                    for (int g = 0; g < 4; ++g)
#pragma unroll
                        for (int k = 0; k < 4; ++k)
                            acc[g] = __builtin_amdgcn_mfma_f32_16x16x32_f16(
                                a[k], B[g][half*4 + k], acc[g], 0, 0, 0);
                }
                // epilogue: lane owns (row0+r, col jj*16+l15)
#pragma unroll
                for (int r = 0; r < 4; ++r) {
                    const int row = row0 + r;
                    const int col = jj*16 + l15;
                    float gi = acc[0][r] + (float)grow[r][0];
                    float gf = acc[1][r] + (float)grow[r][1];
                    float gg = acc[2][r] + (float)grow[r][2];
                    float go = acc[3][r] + (float)grow[r][3];
                    float i_ = 1.f/(1.f + __expf(-gi));
                    float f_ = 1.f/(1.f + __expf(-gf));
                    float zg = __expf(2.f*gg);
                    float g_ = 1.f - 2.f/(zg + 1.f);
                    float o_ = 1.f/(1.f + __expf(-go));
                    const int cidx = row*256 + (col ^ ((row & 4) << 2));  // bank hash
                    float cold = c_lds[cidx];
                    float cn = f_*cold + i_*g_;
                    bool upd = tt < lenr[r];
                    c_lds[cidx] = upd ? cn : cold;
                    float zt = __expf(2.f*cn);
                    float th = 1.f - 2.f/(zt + 1.f);
                    float hnv = o_*th;
                    int hoff = (row*512 + col*2) ^ ((row & 7) << 4);
                    f16 hold = *(const f16*)(hc + hoff);       // last step's h
                    *(f16*)(hb + hoff) = upd ? (f16)hnv : hold;
                }
            }
        }
        __syncthreads();   // all hb-writes visible; all reads of hc done
        unsigned char* tmp = hc; hc = hb; hb = tmp;
        tt += dtt;
    }

    // out: f32 [16384][512]; block writes 32 seqs x its dir's 256 cols
#pragma unroll
    for (int i = 0; i < 32; ++i) {
        int idx  = i*256 + tid;
        int srow = idx >> 8, col = idx & 255;
        int off  = (srow*512 + col*2) ^ ((srow & 7) << 4);
        f16 hv   = *(const f16*)(hc + off);
        out[(size_t)(seq0 + srow)*512 + dir*256 + col] = (float)hv;
    }
}

// ---------------------------------------------------------------------------
extern "C" void kernel_launch(void* const* d_in, const int* in_sizes, int n_in,
                              void* d_out, int out_size, void* d_ws, size_t ws_size,
                              hipStream_t stream) {
    (void)in_sizes; (void)n_in; (void)out_size; (void)ws_size;
    const int*   char_ids = (const int*)d_in[0];
    const int*   lengths  = (const int*)d_in[1];
    const float* emb      = (const float*)d_in[2];
    const float* Wih_f    = (const float*)d_in[3];
    const float* Whh_f    = (const float*)d_in[4];
    const float* b_f      = (const float*)d_in[5];
    const float* Wih_b    = (const float*)d_in[6];
    const float* Whh_b    = (const float*)d_in[7];
    const float* b_b      = (const float*)d_in[8];
    float* out = (float*)d_out;

    f16* gih = (f16*)d_ws;                    // 2*128*256*4 f16 = 512 KB
    f16* bp  = gih + 2 * VOCAB * 1024;        // 2*16*4*8*64*8 f16 = 1 MB

    gih_kernel<<<256, 256, 0, stream>>>(emb, Wih_f, b_f, Wih_b, b_b, gih);
    whh_pack_kernel<<<2048, 256, 0, stream>>>(Whh_f, Whh_b, bp);
    lstm_kernel<<<1024, 256, 0, stream>>>(char_ids, lengths, gih, bp, out);
}

// Round 9
// 570.326 us; speedup vs baseline: 2.0982x; 1.3751x over previous
//
#include <hip/hip_runtime.h>
#include <hip/hip_fp16.h>

#define VOCAB 128
#define TMAX 16
#define NW 16384
#define NGRP 512   // 32-seq groups per direction

typedef _Float16 f16;
typedef _Float16 f16x4 __attribute__((ext_vector_type(4)));
typedef _Float16 f16x8 __attribute__((ext_vector_type(8)));
typedef float f32x4 __attribute__((ext_vector_type(4)));

// ---- kernel 1: gih[dir][v][col(256)][gate(4)] = emb[v].Wih[gate*256+col] + b
__global__ void gih_kernel(const float* __restrict__ emb,
                           const float* __restrict__ WihF, const float* __restrict__ bF,
                           const float* __restrict__ WihB, const float* __restrict__ bB,
                           f16* __restrict__ gih) {
    int dir = blockIdx.x >> 7;      // 256 blocks: 2 dirs x 128 vocab
    int v   = blockIdx.x & 127;
    const float* Wih = dir ? WihB : WihF;
    const float* bb  = dir ? bB : bF;
    __shared__ float ev[128];
    int t = threadIdx.x;            // 256 threads
    if (t < 128) ev[t] = emb[v*128 + t];
    __syncthreads();
#pragma unroll
    for (int qq = 0; qq < 4; ++qq) {
        int g = qq*256 + t;         // gate=qq, col=t
        const float4* w4 = (const float4*)(Wih + (size_t)g * 128);
        float s = bb[g];
#pragma unroll
        for (int e = 0; e < 32; ++e) {
            float4 wv = w4[e];
            s += wv.x*ev[e*4] + wv.y*ev[e*4+1] + wv.z*ev[e*4+2] + wv.w*ev[e*4+3];
        }
        gih[((size_t)(dir*VOCAB + v)*256 + t)*4 + qq] = (f16)s;
    }
}

// ---- kernel 2: pack Whh f32[1024][256] -> f16 bp[dir][jj(16)][gate(4)][kt(8)][lane(64)][e(8)]
__global__ void whh_pack_kernel(const float* __restrict__ WhhF,
                                const float* __restrict__ WhhB,
                                f16* __restrict__ bp) {
    int idx = blockIdx.x * 256 + threadIdx.x;   // grid 2048
    int dir = idx >> 18;
    int rem = idx & 262143;
    int g = rem >> 8;
    int k = rem & 255;
    const float* W = dir ? WhhB : WhhF;
    float val = W[(size_t)g * 256 + k];
    int gate = g >> 8;
    int jj   = (g >> 4) & 15;
    int c15  = g & 15;
    int kt = k >> 5, kr = (k >> 3) & 3, e = k & 7;
    int lane = kr*16 + c15;
    size_t off = ((((size_t)(dir*16 + jj)*4 + gate)*8 + kt)*64 + lane)*8 + e;
    bp[off] = (f16)val;
}

// ---- counting sort by length (16 buckets) -> perm ---------------------------
__global__ void hist_kernel(const int* __restrict__ lengths, int* __restrict__ cnt) {
    __shared__ int h[16];
    int tid = threadIdx.x;
    if (tid < 16) h[tid] = 0;
    __syncthreads();
    int i = blockIdx.x * 256 + tid;           // 64 blocks x 256 = 16384
    atomicAdd(&h[lengths[i] - 1], 1);
    __syncthreads();
    if (tid < 16) atomicAdd(&cnt[tid], h[tid]);
}
__global__ void scan_kernel(const int* __restrict__ cnt, int* __restrict__ base) {
    if (threadIdx.x == 0) {
        int acc = 0;
#pragma unroll
        for (int l = 0; l < 16; ++l) { base[l] = acc; acc += cnt[l]; }
    }
}
__global__ void scatter_kernel(const int* __restrict__ lengths, int* __restrict__ base,
                               int* __restrict__ perm) {
    int i = blockIdx.x * 256 + threadIdx.x;
    int pos = atomicAdd(&base[lengths[i] - 1], 1);
    perm[pos] = i;   // ascending length; order within bucket arbitrary (ok)
}

// ---- kernel 3: LSTM, column-ownership, length-sorted blocks, early exit.
// 1024 blocks x 256 threads (4 waves). Block takes 32 consecutive sorted seqs
// (via perm), runs only smax = max(len in block) steps. LPT: longest first.
// Wave w owns col-tiles jj = w*4+p, p=0..3 (one B[4][8] reg set live).
// h: double-buffered XOR-swizzled LDS; c: bank-hashed LDS; 1 barrier/step.
__global__ __launch_bounds__(256, 1)
void lstm_kernel(const int* __restrict__ char_ids, const int* __restrict__ lengths,
                 const int* __restrict__ perm,
                 const f16* __restrict__ gih, const f16* __restrict__ bp2,
                 float* __restrict__ out) {
    const int dir = blockIdx.x & 1;
    const int grp = (NGRP - 1) - (blockIdx.x >> 1);   // longest-first (LPT)

    __shared__ __align__(16) unsigned char h2[2][16384];   // 2 x [32][256] f16, swizzled
    __shared__ __align__(16) float c_lds[8192];            // [32][256] f32, bank-hashed
    __shared__ int cid_s[512];                             // [32][16]
    __shared__ int len_s[32];
    __shared__ int sid_s[32];
    __shared__ int smax_s;

    const int tid  = threadIdx.x;
    const int lane = tid & 63;
    const int w    = tid >> 6;      // 0..3
    const int l15  = lane & 15;
    const int q    = lane >> 4;

    // prologue
    if (tid == 0) smax_s = 1;
    if (tid < 32) {
        int sid = perm[grp * 32 + tid];
        sid_s[tid] = sid;
        len_s[tid] = lengths[sid];
    }
    {
        float4 z = {0.f, 0.f, 0.f, 0.f};
#pragma unroll
        for (int i = 0; i < 4; ++i) *(float4*)(h2[0] + (i*256 + tid)*16) = z;
#pragma unroll
        for (int i = 0; i < 8; ++i) *(float4*)(c_lds + (i*256 + tid)*4) = z;
    }
    __syncthreads();
    if (tid < 32) atomicMax(&smax_s, len_s[tid]);
#pragma unroll
    for (int i = 0; i < 2; ++i) {
        int idx = i*256 + tid;
        cid_s[idx] = char_ids[(size_t)sid_s[idx >> 4] * 16 + (idx & 15)];
    }
    __syncthreads();
    const int smax = smax_s;

    const f16* bp_d  = bp2 + (size_t)dir * 262144;
    const f16* gih_d = gih + (size_t)dir * 131072;

    unsigned char* hc = h2[0];
    unsigned char* hb = h2[1];

#pragma unroll 1
    for (int s = 0; s < smax; ++s) {
        const int tt = dir ? (smax - 1 - s) : s;   // bwd: smax-1..0 (= ref active window)
#pragma unroll 1
        for (int p = 0; p < 4; ++p) {             // unroll 1: only ONE B set live
            const int jj = w*4 + p;
            const f16* bpj = bp_d + (size_t)jj * 16384;
            f16x8 B[4][8];                         // 128 regs, from L2
#pragma unroll
            for (int g = 0; g < 4; ++g)
#pragma unroll
                for (int kt = 0; kt < 8; ++kt)
                    B[g][kt] = *(const f16x8*)(bpj + ((g*8 + kt)*64 + lane)*8);

#pragma unroll
            for (int m = 0; m < 2; ++m) {
                const int row0 = m*16 + q*4;
                f16x4 grow[4];
                int lenr[4];
#pragma unroll
                for (int r = 0; r < 4; ++r) {
                    int row = row0 + r;
                    int cid = cid_s[row*16 + tt];              // LDS broadcast
                    grow[r] = *(const f16x4*)(gih_d + ((size_t)cid*256 + jj*16 + l15)*4);
                    lenr[r] = len_s[row];
                }
                f32x4 acc[4];
#pragma unroll
                for (int g = 0; g < 4; ++g) acc[g] = (f32x4){0.f,0.f,0.f,0.f};
                const int arow = m*16 + l15;
                const int aswz = (arow & 7) << 4;
#pragma unroll
                for (int half = 0; half < 2; ++half) {
                    f16x8 a[4];
#pragma unroll
                    for (int k = 0; k < 4; ++k) {
                        int off = (arow*512 + ((half*4 + k)*32 + q*8)*2) ^ aswz;
                        a[k] = *(const f16x8*)(hc + off);
                    }
#pragma unroll
                    for (int g = 0; g < 4; ++g)
#pragma unroll
                        for (int k = 0; k < 4; ++k)
                            acc[g] = __builtin_amdgcn_mfma_f32_16x16x32_f16(
                                a[k], B[g][half*4 + k], acc[g], 0, 0, 0);
                }
                // epilogue: lane owns (row0+r, col jj*16+l15)
#pragma unroll
                for (int r = 0; r < 4; ++r) {
                    const int row = row0 + r;
                    const int col = jj*16 + l15;
                    float gi = acc[0][r] + (float)grow[r][0];
                    float gf = acc[1][r] + (float)grow[r][1];
                    float gg = acc[2][r] + (float)grow[r][2];
                    float go = acc[3][r] + (float)grow[r][3];
                    float i_ = 1.f/(1.f + __expf(-gi));
                    float f_ = 1.f/(1.f + __expf(-gf));
                    float zg = __expf(2.f*gg);
                    float g_ = 1.f - 2.f/(zg + 1.f);
                    float o_ = 1.f/(1.f + __expf(-go));
                    const int cidx = row*256 + (col ^ ((row & 4) << 2));  // bank hash
                    float cold = c_lds[cidx];
                    float cn = f_*cold + i_*g_;
                    bool upd = tt < lenr[r];
                    c_lds[cidx] = upd ? cn : cold;
                    float zt = __expf(2.f*cn);
                    float th = 1.f - 2.f/(zt + 1.f);
                    float hnv = o_*th;
                    int hoff = (row*512 + col*2) ^ ((row & 7) << 4);
                    f16 hold = *(const f16*)(hc + hoff);       // last step's h
                    *(f16*)(hb + hoff) = upd ? (f16)hnv : hold;
                }
            }
        }
        __syncthreads();   // all hb-writes visible; all reads of hc done
        unsigned char* tmp = hc; hc = hb; hb = tmp;
    }

    // out: f32 [16384][512]; scatter rows via sid_s (1 KB contiguous per row)
#pragma unroll
    for (int i = 0; i < 32; ++i) {
        int idx  = i*256 + tid;
        int srow = idx >> 8, col = idx & 255;
        int off  = (srow*512 + col*2) ^ ((srow & 7) << 4);
        f16 hv   = *(const f16*)(hc + off);
        out[(size_t)sid_s[srow]*512 + dir*256 + col] = (float)hv;
    }
}

// ---------------------------------------------------------------------------
extern "C" void kernel_launch(void* const* d_in, const int* in_sizes, int n_in,
                              void* d_out, int out_size, void* d_ws, size_t ws_size,
                              hipStream_t stream) {
    (void)in_sizes; (void)n_in; (void)out_size; (void)ws_size;
    const int*   char_ids = (const int*)d_in[0];
    const int*   lengths  = (const int*)d_in[1];
    const float* emb      = (const float*)d_in[2];
    const float* Wih_f    = (const float*)d_in[3];
    const float* Whh_f    = (const float*)d_in[4];
    const float* b_f      = (const float*)d_in[5];
    const float* Wih_b    = (const float*)d_in[6];
    const float* Whh_b    = (const float*)d_in[7];
    const float* b_b      = (const float*)d_in[8];
    float* out = (float*)d_out;

    f16* gih  = (f16*)d_ws;                        // 512 KB
    f16* bp   = gih + 2 * VOCAB * 1024;            // 1 MB
    int* perm = (int*)((char*)d_ws + 1572864);     // 64 KB
    int* cnt  = perm + NW;                         // 16 ints
    int* base = cnt + 16;                          // 16 ints

    gih_kernel<<<256, 256, 0, stream>>>(emb, Wih_f, b_f, Wih_b, b_b, gih);
    whh_pack_kernel<<<2048, 256, 0, stream>>>(Whh_f, Whh_b, bp);
    hipMemsetAsync(cnt, 0, 16 * sizeof(int), stream);
    hist_kernel<<<64, 256, 0, stream>>>(lengths, cnt);
    scan_kernel<<<1, 64, 0, stream>>>(cnt, base);
    scatter_kernel<<<64, 256, 0, stream>>>(lengths, base, perm);
    lstm_kernel<<<1024, 256, 0, stream>>>(char_ids, lengths, perm, gih, bp, out);
}

// Round 12
// 451.321 us; speedup vs baseline: 2.6514x; 1.2637x over previous
//
#include <hip/hip_runtime.h>
#include <hip/hip_fp16.h>

#define VOCAB 128
#define TMAX 16
#define NW 16384
#define NGRP 512   // 32-seq groups per direction

typedef _Float16 f16;
typedef _Float16 f16x4 __attribute__((ext_vector_type(4)));
typedef _Float16 f16x8 __attribute__((ext_vector_type(8)));
typedef float f32x4 __attribute__((ext_vector_type(4)));

#define L2E  1.442695041f
#define L2E2 2.885390082f

// ---- kernel 1: gih[dir][v][col(256)][gate(4)] = (emb[v].Wih[g*256+col]+b)*scale
__global__ void gih_kernel(const float* __restrict__ emb,
                           const float* __restrict__ WihF, const float* __restrict__ bF,
                           const float* __restrict__ WihB, const float* __restrict__ bB,
                           f16* __restrict__ gih) {
    int b = blockIdx.x;                 // 512 = dir(2) x v(128) x half(2)
    int dir = b >> 8, v = (b >> 1) & 127, half = b & 1;
    const float* Wih = dir ? WihB : WihF;
    const float* bb  = dir ? bB : bF;
    __shared__ float ev[128];
    int t = threadIdx.x;                // 256 threads
    if (t < 128) ev[t] = emb[v*128 + t];
    __syncthreads();
#pragma unroll
    for (int q2 = 0; q2 < 2; ++q2) {
        int gate = half*2 + q2;
        int g = gate*256 + t;
        const float4* w4 = (const float4*)(Wih + (size_t)g * 128);
        float s = bb[g];
#pragma unroll
        for (int e = 0; e < 32; ++e) {
            float4 wv = w4[e];
            s += wv.x*ev[e*4] + wv.y*ev[e*4+1] + wv.z*ev[e*4+2] + wv.w*ev[e*4+3];
        }
        float scale = (gate == 2) ? L2E2 : L2E;
        gih[(size_t)(dir*VOCAB + v)*1024 + t*4 + gate] = (f16)(s * scale);
    }
}

// ---- kernel 2: pack Whh -> f16 bp[dir][jj(16)][gate(4)][kt(8)][lane(64)][e(8)], scaled
__global__ void whh_pack_kernel(const float* __restrict__ WhhF,
                                const float* __restrict__ WhhB,
                                f16* __restrict__ bp) {
    int idx = blockIdx.x * 256 + threadIdx.x;   // grid 2048
    int dir = idx >> 18;
    int rem = idx & 262143;
    int g = rem >> 8;
    int k = rem & 255;
    const float* W = dir ? WhhB : WhhF;
    float val = W[(size_t)g * 256 + k];
    int gate = g >> 8;
    int jj   = (g >> 4) & 15;
    int c15  = g & 15;
    int kt = k >> 5, kr = (k >> 3) & 3, e = k & 7;
    int lane = kr*16 + c15;
    float scale = (gate == 2) ? L2E2 : L2E;
    size_t off = ((((size_t)(dir*16 + jj)*4 + gate)*8 + kt)*64 + lane)*8 + e;
    bp[off] = (f16)(val * scale);
}

// ---- counting sort by length -----------------------------------------------
__global__ void hist_kernel(const int* __restrict__ lengths, int* __restrict__ cnt) {
    __shared__ int h[16];
    int tid = threadIdx.x;
    if (tid < 16) h[tid] = 0;
    __syncthreads();
    int i = blockIdx.x * 256 + tid;
    atomicAdd(&h[lengths[i] - 1], 1);
    __syncthreads();
    if (tid < 16) atomicAdd(&cnt[tid], h[tid]);
}
__global__ void scan_kernel(const int* __restrict__ cnt, int* __restrict__ base) {
    if (threadIdx.x == 0) {
        int acc = 0;
#pragma unroll
        for (int l = 0; l < 16; ++l) { base[l] = acc; acc += cnt[l]; }
    }
}
__global__ void scatter_kernel(const int* __restrict__ lengths, int* __restrict__ base,
                               int* __restrict__ perm) {
    __shared__ int lcnt[16];
    __shared__ int lbase[16];
    int tid = threadIdx.x;
    if (tid < 16) lcnt[tid] = 0;
    __syncthreads();
    int i = blockIdx.x * 256 + tid;
    int bkt = lengths[i] - 1;
    int rank = atomicAdd(&lcnt[bkt], 1);        // LDS atomic
    __syncthreads();
    if (tid < 16) lbase[tid] = atomicAdd(&base[tid], lcnt[tid]);  // 16/block
    __syncthreads();
    perm[lbase[bkt] + rank] = i;
}

// ---- kernel 3: LSTM --------------------------------------------------------
// 1024 blocks x 256 threads (4 waves), 32 sorted seqs/block, early exit at
// block-max length, LPT order. Wave w owns jj = w*4+p (4 phases); per phase
// B split in K-halves (B[4][4] = 64 regs, static acc indexing).
// LDS 53 KB (f16 c, padded rows: stride 528 B) -> 3 blocks/CU target.
// h: double-buffered [32][264] f16; c: [32][264] f16; 1 barrier/step.
#define HSTRIDE 528          // (256+8) f16 = 528 B; bank shift 4/row
#define HBUF    16896        // 32*528
#define CBASE   33792        // after h2[2]
#define CIDB    50688
#define SIDB    52736
#define LENB    52864
#define SMAXB   52992

__global__ __launch_bounds__(256)
__attribute__((amdgpu_waves_per_eu(3, 4)))
void lstm_kernel(const int* __restrict__ char_ids, const int* __restrict__ lengths,
                 const int* __restrict__ perm,
                 const f16* __restrict__ gih, const f16* __restrict__ bp2,
                 float* __restrict__ out) {
    const int dir = blockIdx.x & 1;
    const int grp = (NGRP - 1) - (blockIdx.x >> 1);   // longest-first (LPT)

    __shared__ __align__(16) unsigned char lds[53248];
    int* cid_s = (int*)(lds + CIDB);
    int* sid_s = (int*)(lds + SIDB);
    int* len_s = (int*)(lds + LENB);
    int* smax_s = (int*)(lds + SMAXB);

    const int tid  = threadIdx.x;
    const int lane = tid & 63;
    const int w    = tid >> 6;      // 0..3
    const int l15  = lane & 15;
    const int q    = lane >> 4;

    if (tid == 0) *smax_s = 1;
    if (tid < 32) {
        int sid = perm[grp * 32 + tid];
        sid_s[tid] = sid;
        len_s[tid] = lengths[sid];
    }
    {   // zero h2 + c: 50688 B = 3168 float4
        float4 z = {0.f, 0.f, 0.f, 0.f};
#pragma unroll
        for (int i = 0; i < 13; ++i) {
            int idx = i*256 + tid;
            if (idx < 3168) *(float4*)(lds + idx*16) = z;
        }
    }
    __syncthreads();
    if (tid < 32) atomicMax(smax_s, len_s[tid]);
#pragma unroll
    for (int i = 0; i < 2; ++i) {
        int idx = i*256 + tid;
        cid_s[idx] = char_ids[(size_t)sid_s[idx >> 4] * 16 + (idx & 15)];
    }
    __syncthreads();
    const int smax = *smax_s;

    const f16* bp_d  = bp2 + (size_t)dir * 262144;
    const f16* gih_d = gih + (size_t)dir * 131072;

    int lenp[2][4];
#pragma unroll
    for (int m = 0; m < 2; ++m)
#pragma unroll
        for (int r = 0; r < 4; ++r) lenp[m][r] = len_s[m*16 + q*4 + r];

    unsigned int hcb = 0;           // current h buffer base (0 / 16896)

#pragma unroll 1
    for (int s = 0; s < smax; ++s) {
        const int tt = dir ? (smax - 1 - s) : s;
        int cidp[2][4];
#pragma unroll
        for (int m = 0; m < 2; ++m)
#pragma unroll
            for (int r = 0; r < 4; ++r)
                cidp[m][r] = cid_s[(m*16 + q*4 + r)*16 + tt];

#pragma unroll 1
        for (int p = 0; p < 4; ++p) {
            const int jj = w*4 + p;
            const f16* bpj = bp_d + (size_t)jj * 16384;

            f32x4 acc[2][4];
#pragma unroll
            for (int m = 0; m < 2; ++m)
#pragma unroll
                for (int g = 0; g < 4; ++g) acc[m][g] = (f32x4){0.f,0.f,0.f,0.f};

#pragma unroll 1
            for (int kh = 0; kh < 2; ++kh) {       // K-halves: one B[4][4] live
                f16x8 B[4][4];
#pragma unroll
                for (int g = 0; g < 4; ++g)
#pragma unroll
                    for (int k = 0; k < 4; ++k)
                        B[g][k] = *(const f16x8*)(bpj + ((g*8 + kh*4 + k)*64 + lane)*8);
#pragma unroll
                for (int m = 0; m < 2; ++m) {
                    f16x8 a[4];
#pragma unroll
                    for (int k = 0; k < 4; ++k)
                        a[k] = *(const f16x8*)(lds + hcb + (m*16 + l15)*HSTRIDE
                                               + ((kh*4 + k)*32 + q*8)*2);
#pragma unroll
                    for (int g = 0; g < 4; ++g)
#pragma unroll
                        for (int k = 0; k < 4; ++k)
                            acc[m][g] = __builtin_amdgcn_mfma_f32_16x16x32_f16(
                                a[k], B[g][k], acc[m][g], 0, 0, 0);
                }
            }

            // epilogue (B regs dead here; grow reuses them)
            const int col = jj*16 + l15;
#pragma unroll
            for (int m = 0; m < 2; ++m) {
                f16x4 grow[4];
#pragma unroll
                for (int r = 0; r < 4; ++r)
                    grow[r] = *(const f16x4*)(gih_d + (size_t)cidp[m][r]*1024 + col*4);
#pragma unroll
                for (int r = 0; r < 4; ++r) {
                    const int row = m*16 + q*4 + r;
                    const int voff = row*HSTRIDE + col*2;
                    float gi = acc[m][0][r] + (float)grow[r][0];
                    float gf = acc[m][1][r] + (float)grow[r][1];
                    float gg = acc[m][2][r] + (float)grow[r][2];
                    float go = acc[m][3][r] + (float)grow[r][3];
                    float i_ = 1.f/(1.f + exp2f(-gi));     // gates pre-scaled by log2e
                    float f_ = 1.f/(1.f + exp2f(-gf));
                    float g_ = 1.f - 2.f/(exp2f(gg) + 1.f); // gg pre-scaled by 2*log2e
                    float o_ = 1.f/(1.f + exp2f(-go));
                    f16 cold16 = *(const f16*)(lds + CBASE + voff);
                    float cn = f_*(float)cold16 + i_*g_;
                    float th = 1.f - 2.f/(exp2f(cn * L2E2) + 1.f);
                    float hn = o_*th;
                    f16 cw, hw;
                    if (tt < lenp[m][r]) {                 // usually uniform-true
                        cw = (f16)cn; hw = (f16)hn;
                    } else {                               // execz-skipped mostly
                        cw = cold16;
                        hw = *(const f16*)(lds + hcb + voff);
                    }
                    *(f16*)(lds + CBASE + voff) = cw;
                    *(f16*)(lds + (hcb ^ HBUF) + voff) = hw;
                }
            }
        }
        __syncthreads();
        hcb ^= HBUF;
    }

    // out: f32 [16384][512]; scatter rows via sid_s
#pragma unroll
    for (int i = 0; i < 32; ++i) {
        int idx  = i*256 + tid;
        int srow = idx >> 8, c2 = idx & 255;
        f16 hv = *(const f16*)(lds + hcb + srow*HSTRIDE + c2*2);
        out[(size_t)sid_s[srow]*512 + dir*256 + c2] = (float)hv;
    }
}

// ---------------------------------------------------------------------------
extern "C" void kernel_launch(void* const* d_in, const int* in_sizes, int n_in,
                              void* d_out, int out_size, void* d_ws, size_t ws_size,
                              hipStream_t stream) {
    (void)in_sizes; (void)n_in; (void)out_size; (void)ws_size;
    const int*   char_ids = (const int*)d_in[0];
    const int*   lengths  = (const int*)d_in[1];
    const float* emb      = (const float*)d_in[2];
    const float* Wih_f    = (const float*)d_in[3];
    const float* Whh_f    = (const float*)d_in[4];
    const float* b_f      = (const float*)d_in[5];
    const float* Wih_b    = (const float*)d_in[6];
    const float* Whh_b    = (const float*)d_in[7];
    const float* b_b      = (const float*)d_in[8];
    float* out = (float*)d_out;

    f16* gih  = (f16*)d_ws;                        // 512 KB
    f16* bp   = gih + 2 * VOCAB * 1024;            // 1 MB
    int* perm = (int*)((char*)d_ws + 1572864);     // 64 KB
    int* cnt  = perm + NW;
    int* base = cnt + 16;

    gih_kernel<<<512, 256, 0, stream>>>(emb, Wih_f, b_f, Wih_b, b_b, gih);
    whh_pack_kernel<<<2048, 256, 0, stream>>>(Whh_f, Whh_b, bp);
    hipMemsetAsync(cnt, 0, 16 * sizeof(int), stream);
    hist_kernel<<<64, 256, 0, stream>>>(lengths, cnt);
    scan_kernel<<<1, 64, 0, stream>>>(cnt, base);
    scatter_kernel<<<64, 256, 0, stream>>>(lengths, base, perm);
    lstm_kernel<<<1024, 256, 0, stream>>>(char_ids, lengths, perm, gih, bp, out);
}